// Round 1
// baseline (1558.584 us; speedup 1.0000x reference)
//
#include <hip/hip_runtime.h>
#include <hip/hip_bf16.h>

// ---------------------------------------------------------------------------
// GCN forward: 3x { h = A_hat @ (x W) + b ; relu } -> mean-pool(64) -> MLP(5)
// N=100000 nodes, E=3200000 edges, C=H=128.
// Strategy: build CSR-by-dst once per launch (no f32 atomics in hot loop),
// wave-per-node gather-aggregate (h is L3-resident: 51 MB), f32 vector GEMM
// with W staged in LDS (no fp32 MFMA on CDNA4).
// ---------------------------------------------------------------------------

#define CH 128

// ---------------- degree count ----------------
__global__ void k_count(const int* __restrict__ dst, int e, int* __restrict__ cnt) {
    int i = blockIdx.x * blockDim.x + threadIdx.x;
    if (i < e) atomicAdd(&cnt[dst[i]], 1);
}

// ---------------- hierarchical prefix scan (chunk=1024) ----------------
__global__ void k_scan_reduce(const int* __restrict__ cnt, int n, int* __restrict__ bsums) {
    __shared__ int sd[256];
    int b = blockIdx.x, t = threadIdx.x;
    int base = b * 1024;
    int s = 0;
    for (int i = t; i < 1024; i += 256) {
        int idx = base + i;
        if (idx < n) s += cnt[idx];
    }
    sd[t] = s; __syncthreads();
    for (int st = 128; st > 0; st >>= 1) {
        if (t < st) sd[t] += sd[t + st];
        __syncthreads();
    }
    if (t == 0) bsums[b] = sd[0];
}

__global__ void k_scan_bsums(const int* __restrict__ bsums, int nb, int* __restrict__ boffs) {
    __shared__ int sd[256];
    int t = threadIdx.x;
    int v = (t < nb) ? bsums[t] : 0;
    sd[t] = v; __syncthreads();
    for (int st = 1; st < 256; st <<= 1) {
        int x = (t >= st) ? sd[t - st] : 0;
        __syncthreads();
        sd[t] += x;
        __syncthreads();
    }
    if (t < nb) boffs[t] = sd[t] - v;   // exclusive
}

__global__ void k_scan_final(const int* __restrict__ cnt, int n,
                             const int* __restrict__ boffs, int* __restrict__ offs) {
    __shared__ int sd[256];
    int b = blockIdx.x, t = threadIdx.x;
    int base = b * 1024 + t * 4;
    int v[4]; int s = 0;
#pragma unroll
    for (int i = 0; i < 4; ++i) {
        int idx = base + i;
        v[i] = (idx < n) ? cnt[idx] : 0;
        s += v[i];
    }
    sd[t] = s; __syncthreads();
    for (int st = 1; st < 256; st <<= 1) {
        int x = (t >= st) ? sd[t - st] : 0;
        __syncthreads();
        sd[t] += x;
        __syncthreads();
    }
    int excl = sd[t] - s + boffs[b];
#pragma unroll
    for (int i = 0; i < 4; ++i) {
        int idx = base + i;
        if (idx < n) offs[idx] = excl;
        excl += v[i];
    }
}

// ---------------- norms + offs[n]=E ----------------
__global__ void k_norm(const int* __restrict__ cnt, int n,
                       float* __restrict__ dinv, float* __restrict__ invdeg,
                       int* __restrict__ offs, int e) {
    int i = blockIdx.x * blockDim.x + threadIdx.x;
    if (i >= n) return;
    float d = (float)cnt[i] + 1.0f;
    dinv[i]   = 1.0f / sqrtf(d);
    invdeg[i] = 1.0f / d;
    if (i == 0) offs[n] = e;
}

// ---------------- CSR fill ----------------
__global__ void k_fill(const int* __restrict__ src, const int* __restrict__ dst, int e,
                       const int* __restrict__ offs, int* __restrict__ cursor,
                       int* __restrict__ col) {
    int i = blockIdx.x * blockDim.x + threadIdx.x;
    if (i >= e) return;
    int d = dst[i];
    int pos = atomicAdd(&cursor[d], 1);
    col[offs[d] + pos] = src[i];
}

// ---------------- GEMM: out[N,128] = A[N,128] @ W[128,128] ----------------
// 256 threads, 64 rows/block. W staged in LDS (64 KB -> 2 blocks/CU).
// thread t: cols (t&31)*4 .. +3 (float4), rows rowbase + (t>>5)*8 .. +7.
__global__ __launch_bounds__(256) void k_gemm(const float* __restrict__ A,
                                              const float* __restrict__ W,
                                              float* __restrict__ out, int n) {
    __shared__ float Ws[CH * CH];
    int t = threadIdx.x;
    for (int i = t * 4; i < CH * CH; i += 256 * 4)
        *(float4*)&Ws[i] = *(const float4*)&W[i];
    __syncthreads();

    int rowbase = blockIdx.x * 64;
    int cg = (t & 31) * 4;
    int rg = (t >> 5) * 8;
    float acc[8][4] = {{0.f}};

    for (int k4 = 0; k4 < 32; ++k4) {
        int k = k4 * 4;
        float4 w0 = *(float4*)&Ws[(k + 0) * CH + cg];
        float4 w1 = *(float4*)&Ws[(k + 1) * CH + cg];
        float4 w2 = *(float4*)&Ws[(k + 2) * CH + cg];
        float4 w3 = *(float4*)&Ws[(k + 3) * CH + cg];
#pragma unroll
        for (int j = 0; j < 8; ++j) {
            int row = rowbase + rg + j;
            int rr = row < n ? row : n - 1;           // clamp OOB reads
            float4 xv = *(const float4*)&A[(size_t)rr * CH + k];
            acc[j][0] += xv.x * w0.x + xv.y * w1.x + xv.z * w2.x + xv.w * w3.x;
            acc[j][1] += xv.x * w0.y + xv.y * w1.y + xv.z * w2.y + xv.w * w3.y;
            acc[j][2] += xv.x * w0.z + xv.y * w1.z + xv.z * w2.z + xv.w * w3.z;
            acc[j][3] += xv.x * w0.w + xv.y * w1.w + xv.z * w2.w + xv.w * w3.w;
        }
    }
#pragma unroll
    for (int j = 0; j < 8; ++j) {
        int row = rowbase + rg + j;
        if (row < n) {
            float4 o = make_float4(acc[j][0], acc[j][1], acc[j][2], acc[j][3]);
            *(float4*)&out[(size_t)row * CH + cg] = o;
        }
    }
}

// ---------------- aggregation: wave per node, lane = 2 channels ----------------
// out[i] = relu( dinv[i] * sum_e dinv[src_e]*h[src_e] + invdeg[i]*h[i] + b )
__global__ __launch_bounds__(256) void k_agg(const float* __restrict__ h,
                                             const int* __restrict__ offs,
                                             const int* __restrict__ col,
                                             const float* __restrict__ dinv,
                                             const float* __restrict__ invdeg,
                                             const float* __restrict__ bias,
                                             float* __restrict__ out, int n) {
    int wave = (int)((blockIdx.x * (unsigned)blockDim.x + threadIdx.x) >> 6);
    int lane = threadIdx.x & 63;
    if (wave >= n) return;
    int i = wave;
    int beg = offs[i], end = offs[i + 1];

    const float2* hp = (const float2*)h;
    float2 acc = make_float2(0.f, 0.f);

    for (int e0 = beg; e0 < end; e0 += 64) {
        int cnt = end - e0; if (cnt > 64) cnt = 64;
        int   s_l = 0;
        float n_l = 0.f;
        if (lane < cnt) {
            s_l = col[e0 + lane];
            n_l = dinv[s_l];
        }
        for (int j = 0; j < cnt; ++j) {
            int   s  = __shfl(s_l, j);
            float nm = __shfl(n_l, j);
            float2 hv = hp[(size_t)s * 64 + lane];
            acc.x += nm * hv.x;
            acc.y += nm * hv.y;
        }
    }

    float di  = dinv[i];
    float idg = invdeg[i];
    float2 hs = hp[(size_t)i * 64 + lane];
    float2 b2 = ((const float2*)bias)[lane];
    float ox = acc.x * di + hs.x * idg + b2.x;
    float oy = acc.y * di + hs.y * idg + b2.y;
    ((float2*)out)[(size_t)i * 64 + lane] = make_float2(fmaxf(ox, 0.f), fmaxf(oy, 0.f));
}

// ---------------- pooling: sorted batch ids, per-block running sums ----------------
#define POOL_CHUNK 512
__global__ __launch_bounds__(128) void k_pool(const float* __restrict__ act,
                                              const int* __restrict__ batch, int n,
                                              float* __restrict__ sums, int* __restrict__ cnts) {
    int b = blockIdx.x, c = threadIdx.x;
    int beg = b * POOL_CHUNK;
    int end = beg + POOL_CHUNK; if (end > n) end = n;
    if (beg >= end) return;

    float acc = 0.f;
    int g = batch[beg];
    int cstart = beg;
    for (int i = beg; i < end; ++i) {
        int gi = batch[i];
        if (gi != g) {
            atomicAdd(&sums[g * CH + c], acc);
            if (c == 0) atomicAdd(&cnts[g], i - cstart);
            acc = 0.f; g = gi; cstart = i;
        }
        acc += act[(size_t)i * CH + c];
    }
    atomicAdd(&sums[g * CH + c], acc);
    if (c == 0) atomicAdd(&cnts[g], end - cstart);
}

// ---------------- MLP head ----------------
__global__ __launch_bounds__(128) void k_mlp(const float* __restrict__ sums,
                                             const int* __restrict__ cnts,
                                             const float* __restrict__ Wm1,
                                             const float* __restrict__ bm1,
                                             const float* __restrict__ Wm2,
                                             const float* __restrict__ bm2,
                                             float* __restrict__ out) {
    int g = blockIdx.x, c = threadIdx.x;
    __shared__ float p[CH];
    __shared__ float hid[CH];
    float invc = 1.0f / fmaxf((float)cnts[g], 1.0f);
    p[c] = sums[g * CH + c] * invc;
    __syncthreads();
    float acc = bm1[c];
    for (int k = 0; k < CH; ++k) acc += p[k] * Wm1[k * CH + c];
    hid[c] = fmaxf(acc, 0.f);
    __syncthreads();
    if (c < 5) {
        float o = bm2[c];
        for (int k = 0; k < CH; ++k) o += hid[k] * Wm2[k * 5 + c];
        out[g * 5 + c] = o;
    }
}

// ---------------------------------------------------------------------------
extern "C" void kernel_launch(void* const* d_in, const int* in_sizes, int n_in,
                              void* d_out, int out_size, void* d_ws, size_t ws_size,
                              hipStream_t stream) {
    const float* x     = (const float*)d_in[0];
    const int*   ei    = (const int*)d_in[1];
    const int*   batch = (const int*)d_in[2];
    const float* W_in  = (const float*)d_in[3];
    const float* b_in  = (const float*)d_in[4];
    const float* W_hid = (const float*)d_in[5];
    const float* b_hid = (const float*)d_in[6];
    const float* Wm1   = (const float*)d_in[7];
    const float* bm1   = (const float*)d_in[8];
    const float* Wm2   = (const float*)d_in[9];
    const float* bm2   = (const float*)d_in[10];

    int n = in_sizes[0] / CH;       // 100000
    int e = in_sizes[1] / 2;        // 3200000
    const int* src = ei;
    const int* dst = ei + e;

    // workspace carve (256B aligned)
    char* p = (char*)d_ws;
    auto carve = [&](size_t bytes) {
        void* r = (void*)p;
        p += (bytes + 255) & ~(size_t)255;
        return r;
    };
    float* h      = (float*)carve((size_t)n * CH * 4);
    float* act    = (float*)carve((size_t)n * CH * 4);
    int*   col    = (int*)  carve((size_t)e * 4);
    int*   cnt    = (int*)  carve((size_t)n * 4);
    int*   cursor = (int*)  carve((size_t)n * 4);
    int*   offs   = (int*)  carve((size_t)(n + 1) * 4);
    float* dinv   = (float*)carve((size_t)n * 4);
    float* invdeg = (float*)carve((size_t)n * 4);
    int*   bsums  = (int*)  carve(256 * 4);
    int*   boffs  = (int*)  carve(256 * 4);
    float* sums   = (float*)carve(64 * CH * 4);
    int*   cnts   = (int*)  carve(64 * 4);

    hipMemsetAsync(cnt,    0, (size_t)n * 4, stream);
    hipMemsetAsync(cursor, 0, (size_t)n * 4, stream);
    hipMemsetAsync(sums,   0, 64 * CH * 4, stream);
    hipMemsetAsync(cnts,   0, 64 * 4, stream);

    int nb = (n + 1023) / 1024;
    k_count      <<<(e + 255) / 256, 256, 0, stream>>>(dst, e, cnt);
    k_scan_reduce<<<nb, 256, 0, stream>>>(cnt, n, bsums);
    k_scan_bsums <<<1, 256, 0, stream>>>(bsums, nb, boffs);
    k_scan_final <<<nb, 256, 0, stream>>>(cnt, n, boffs, offs);
    k_norm       <<<(n + 255) / 256, 256, 0, stream>>>(cnt, n, dinv, invdeg, offs, e);
    k_fill       <<<(e + 255) / 256, 256, 0, stream>>>(src, dst, e, offs, cursor, col);

    dim3 ggemm((n + 63) / 64);
    dim3 gagg((n + 3) / 4);   // 4 waves per 256-thread block, wave per node

    // layer 1
    k_gemm<<<ggemm, 256, 0, stream>>>(x, W_in, h, n);
    k_agg <<<gagg, 256, 0, stream>>>(h, offs, col, dinv, invdeg, b_in, act, n);
    // layer 2
    k_gemm<<<ggemm, 256, 0, stream>>>(act, W_hid, h, n);
    k_agg <<<gagg, 256, 0, stream>>>(h, offs, col, dinv, invdeg, b_hid, act, n);
    // layer 3
    k_gemm<<<ggemm, 256, 0, stream>>>(act, W_hid + CH * CH, h, n);
    k_agg <<<gagg, 256, 0, stream>>>(h, offs, col, dinv, invdeg, b_hid + CH, act, n);

    // pool + head
    k_pool<<<(n + POOL_CHUNK - 1) / POOL_CHUNK, 128, 0, stream>>>(act, batch, n, sums, cnts);
    k_mlp <<<64, 128, 0, stream>>>(sums, cnts, Wm1, bm1, Wm2, bm2, (float*)d_out);
}

// Round 2
// 1502.173 us; speedup vs baseline: 1.0376x; 1.0376x over previous
//
#include <hip/hip_runtime.h>
#include <hip/hip_bf16.h>

// ---------------------------------------------------------------------------
// GCN forward: 3x { h = A_hat @ (x W) + b ; relu } -> mean-pool(64) -> MLP(5)
// N=100000 nodes, E=3200000 edges, C=H=128.
// R1: k_agg restructured — half-wave (32 lanes) per node, float4/lane,
// edge loop unrolled x4 (4 independent 512B row-gathers in flight per group).
// Baseline k_agg had VGPR=12 -> one load in flight -> latency-bound.
// ---------------------------------------------------------------------------

#define CH 128

// ---------------- degree count ----------------
__global__ void k_count(const int* __restrict__ dst, int e, int* __restrict__ cnt) {
    int i = blockIdx.x * blockDim.x + threadIdx.x;
    if (i < e) atomicAdd(&cnt[dst[i]], 1);
}

// ---------------- hierarchical prefix scan (chunk=1024) ----------------
__global__ void k_scan_reduce(const int* __restrict__ cnt, int n, int* __restrict__ bsums) {
    __shared__ int sd[256];
    int b = blockIdx.x, t = threadIdx.x;
    int base = b * 1024;
    int s = 0;
    for (int i = t; i < 1024; i += 256) {
        int idx = base + i;
        if (idx < n) s += cnt[idx];
    }
    sd[t] = s; __syncthreads();
    for (int st = 128; st > 0; st >>= 1) {
        if (t < st) sd[t] += sd[t + st];
        __syncthreads();
    }
    if (t == 0) bsums[b] = sd[0];
}

__global__ void k_scan_bsums(const int* __restrict__ bsums, int nb, int* __restrict__ boffs) {
    __shared__ int sd[256];
    int t = threadIdx.x;
    int v = (t < nb) ? bsums[t] : 0;
    sd[t] = v; __syncthreads();
    for (int st = 1; st < 256; st <<= 1) {
        int x = (t >= st) ? sd[t - st] : 0;
        __syncthreads();
        sd[t] += x;
        __syncthreads();
    }
    if (t < nb) boffs[t] = sd[t] - v;   // exclusive
}

__global__ void k_scan_final(const int* __restrict__ cnt, int n,
                             const int* __restrict__ boffs, int* __restrict__ offs) {
    __shared__ int sd[256];
    int b = blockIdx.x, t = threadIdx.x;
    int base = b * 1024 + t * 4;
    int v[4]; int s = 0;
#pragma unroll
    for (int i = 0; i < 4; ++i) {
        int idx = base + i;
        v[i] = (idx < n) ? cnt[idx] : 0;
        s += v[i];
    }
    sd[t] = s; __syncthreads();
    for (int st = 1; st < 256; st <<= 1) {
        int x = (t >= st) ? sd[t - st] : 0;
        __syncthreads();
        sd[t] += x;
        __syncthreads();
    }
    int excl = sd[t] - s + boffs[b];
#pragma unroll
    for (int i = 0; i < 4; ++i) {
        int idx = base + i;
        if (idx < n) offs[idx] = excl;
        excl += v[i];
    }
}

// ---------------- norms + offs[n]=E ----------------
__global__ void k_norm(const int* __restrict__ cnt, int n,
                       float* __restrict__ dinv, float* __restrict__ invdeg,
                       int* __restrict__ offs, int e) {
    int i = blockIdx.x * blockDim.x + threadIdx.x;
    if (i >= n) return;
    float d = (float)cnt[i] + 1.0f;
    dinv[i]   = 1.0f / sqrtf(d);
    invdeg[i] = 1.0f / d;
    if (i == 0) offs[n] = e;
}

// ---------------- CSR fill ----------------
__global__ void k_fill(const int* __restrict__ src, const int* __restrict__ dst, int e,
                       const int* __restrict__ offs, int* __restrict__ cursor,
                       int* __restrict__ col) {
    int i = blockIdx.x * blockDim.x + threadIdx.x;
    if (i >= e) return;
    int d = dst[i];
    int pos = atomicAdd(&cursor[d], 1);
    col[offs[d] + pos] = src[i];
}

// ---------------- GEMM: out[N,128] = A[N,128] @ W[128,128] ----------------
__global__ __launch_bounds__(256) void k_gemm(const float* __restrict__ A,
                                              const float* __restrict__ W,
                                              float* __restrict__ out, int n) {
    __shared__ float Ws[CH * CH];
    int t = threadIdx.x;
    for (int i = t * 4; i < CH * CH; i += 256 * 4)
        *(float4*)&Ws[i] = *(const float4*)&W[i];
    __syncthreads();

    int rowbase = blockIdx.x * 64;
    int cg = (t & 31) * 4;
    int rg = (t >> 5) * 8;
    float acc[8][4] = {{0.f}};

    for (int k4 = 0; k4 < 32; ++k4) {
        int k = k4 * 4;
        float4 w0 = *(float4*)&Ws[(k + 0) * CH + cg];
        float4 w1 = *(float4*)&Ws[(k + 1) * CH + cg];
        float4 w2 = *(float4*)&Ws[(k + 2) * CH + cg];
        float4 w3 = *(float4*)&Ws[(k + 3) * CH + cg];
#pragma unroll
        for (int j = 0; j < 8; ++j) {
            int row = rowbase + rg + j;
            int rr = row < n ? row : n - 1;           // clamp OOB reads
            float4 xv = *(const float4*)&A[(size_t)rr * CH + k];
            acc[j][0] += xv.x * w0.x + xv.y * w1.x + xv.z * w2.x + xv.w * w3.x;
            acc[j][1] += xv.x * w0.y + xv.y * w1.y + xv.z * w2.y + xv.w * w3.y;
            acc[j][2] += xv.x * w0.z + xv.y * w1.z + xv.z * w2.z + xv.w * w3.z;
            acc[j][3] += xv.x * w0.w + xv.y * w1.w + xv.z * w2.w + xv.w * w3.w;
        }
    }
#pragma unroll
    for (int j = 0; j < 8; ++j) {
        int row = rowbase + rg + j;
        if (row < n) {
            float4 o = make_float4(acc[j][0], acc[j][1], acc[j][2], acc[j][3]);
            *(float4*)&out[(size_t)row * CH + cg] = o;
        }
    }
}

// ---------------- aggregation: half-wave (32 lanes) per node, float4/lane --
// out[i] = relu( dinv[i] * sum_e dinv[src_e]*h[src_e] + invdeg[i]*h[i] + b )
// Edge loop unrolled x4: 4 independent 512B row loads in flight per group.
__global__ __launch_bounds__(256) void k_agg(const float* __restrict__ h,
                                             const int* __restrict__ offs,
                                             const int* __restrict__ col,
                                             const float* __restrict__ dinv,
                                             const float* __restrict__ invdeg,
                                             const float* __restrict__ bias,
                                             float* __restrict__ out, int n) {
    int hw   = (int)((blockIdx.x * (unsigned)blockDim.x + threadIdx.x) >> 5);
    int lane = threadIdx.x & 31;
    if (hw >= n) return;
    int i = hw;
    int beg = offs[i], end = offs[i + 1];

    const float4* hp = (const float4*)h;
    float4 acc = make_float4(0.f, 0.f, 0.f, 0.f);

    for (int e0 = beg; e0 < end; e0 += 32) {
        int cnt = end - e0; if (cnt > 32) cnt = 32;
        int   s_l = 0;
        float n_l = 0.f;
        if (lane < cnt) {
            s_l = col[e0 + lane];
            n_l = dinv[s_l];
        }
        int j = 0;
        for (; j + 4 <= cnt; j += 4) {
            int   s0 = __shfl(s_l, j + 0, 32);
            int   s1 = __shfl(s_l, j + 1, 32);
            int   s2 = __shfl(s_l, j + 2, 32);
            int   s3 = __shfl(s_l, j + 3, 32);
            float w0 = __shfl(n_l, j + 0, 32);
            float w1 = __shfl(n_l, j + 1, 32);
            float w2 = __shfl(n_l, j + 2, 32);
            float w3 = __shfl(n_l, j + 3, 32);
            float4 a0 = hp[(size_t)s0 * 32 + lane];
            float4 a1 = hp[(size_t)s1 * 32 + lane];
            float4 a2 = hp[(size_t)s2 * 32 + lane];
            float4 a3 = hp[(size_t)s3 * 32 + lane];
            acc.x += w0 * a0.x; acc.y += w0 * a0.y; acc.z += w0 * a0.z; acc.w += w0 * a0.w;
            acc.x += w1 * a1.x; acc.y += w1 * a1.y; acc.z += w1 * a1.z; acc.w += w1 * a1.w;
            acc.x += w2 * a2.x; acc.y += w2 * a2.y; acc.z += w2 * a2.z; acc.w += w2 * a2.w;
            acc.x += w3 * a3.x; acc.y += w3 * a3.y; acc.z += w3 * a3.z; acc.w += w3 * a3.w;
        }
        for (; j < cnt; ++j) {
            int   s  = __shfl(s_l, j, 32);
            float nm = __shfl(n_l, j, 32);
            float4 av = hp[(size_t)s * 32 + lane];
            acc.x += nm * av.x; acc.y += nm * av.y; acc.z += nm * av.z; acc.w += nm * av.w;
        }
    }

    float di  = dinv[i];
    float idg = invdeg[i];
    float4 hs = hp[(size_t)i * 32 + lane];
    float4 b4 = ((const float4*)bias)[lane];
    float4 o;
    o.x = fmaxf(acc.x * di + hs.x * idg + b4.x, 0.f);
    o.y = fmaxf(acc.y * di + hs.y * idg + b4.y, 0.f);
    o.z = fmaxf(acc.z * di + hs.z * idg + b4.z, 0.f);
    o.w = fmaxf(acc.w * di + hs.w * idg + b4.w, 0.f);
    ((float4*)out)[(size_t)i * 32 + lane] = o;
}

// ---------------- pooling: sorted batch ids, per-block running sums ----------------
#define POOL_CHUNK 512
__global__ __launch_bounds__(128) void k_pool(const float* __restrict__ act,
                                              const int* __restrict__ batch, int n,
                                              float* __restrict__ sums, int* __restrict__ cnts) {
    int b = blockIdx.x, c = threadIdx.x;
    int beg = b * POOL_CHUNK;
    int end = beg + POOL_CHUNK; if (end > n) end = n;
    if (beg >= end) return;

    float acc = 0.f;
    int g = batch[beg];
    int cstart = beg;
    for (int i = beg; i < end; ++i) {
        int gi = batch[i];
        if (gi != g) {
            atomicAdd(&sums[g * CH + c], acc);
            if (c == 0) atomicAdd(&cnts[g], i - cstart);
            acc = 0.f; g = gi; cstart = i;
        }
        acc += act[(size_t)i * CH + c];
    }
    atomicAdd(&sums[g * CH + c], acc);
    if (c == 0) atomicAdd(&cnts[g], end - cstart);
}

// ---------------- MLP head ----------------
__global__ __launch_bounds__(128) void k_mlp(const float* __restrict__ sums,
                                             const int* __restrict__ cnts,
                                             const float* __restrict__ Wm1,
                                             const float* __restrict__ bm1,
                                             const float* __restrict__ Wm2,
                                             const float* __restrict__ bm2,
                                             float* __restrict__ out) {
    int g = blockIdx.x, c = threadIdx.x;
    __shared__ float p[CH];
    __shared__ float hid[CH];
    float invc = 1.0f / fmaxf((float)cnts[g], 1.0f);
    p[c] = sums[g * CH + c] * invc;
    __syncthreads();
    float acc = bm1[c];
    for (int k = 0; k < CH; ++k) acc += p[k] * Wm1[k * CH + c];
    hid[c] = fmaxf(acc, 0.f);
    __syncthreads();
    if (c < 5) {
        float o = bm2[c];
        for (int k = 0; k < CH; ++k) o += hid[k] * Wm2[k * 5 + c];
        out[g * 5 + c] = o;
    }
}

// ---------------------------------------------------------------------------
extern "C" void kernel_launch(void* const* d_in, const int* in_sizes, int n_in,
                              void* d_out, int out_size, void* d_ws, size_t ws_size,
                              hipStream_t stream) {
    const float* x     = (const float*)d_in[0];
    const int*   ei    = (const int*)d_in[1];
    const int*   batch = (const int*)d_in[2];
    const float* W_in  = (const float*)d_in[3];
    const float* b_in  = (const float*)d_in[4];
    const float* W_hid = (const float*)d_in[5];
    const float* b_hid = (const float*)d_in[6];
    const float* Wm1   = (const float*)d_in[7];
    const float* bm1   = (const float*)d_in[8];
    const float* Wm2   = (const float*)d_in[9];
    const float* bm2   = (const float*)d_in[10];

    int n = in_sizes[0] / CH;       // 100000
    int e = in_sizes[1] / 2;        // 3200000
    const int* src = ei;
    const int* dst = ei + e;

    // workspace carve (256B aligned)
    char* p = (char*)d_ws;
    auto carve = [&](size_t bytes) {
        void* r = (void*)p;
        p += (bytes + 255) & ~(size_t)255;
        return r;
    };
    float* h      = (float*)carve((size_t)n * CH * 4);
    float* act    = (float*)carve((size_t)n * CH * 4);
    int*   col    = (int*)  carve((size_t)e * 4);
    int*   cnt    = (int*)  carve((size_t)n * 4);
    int*   cursor = (int*)  carve((size_t)n * 4);
    int*   offs   = (int*)  carve((size_t)(n + 1) * 4);
    float* dinv   = (float*)carve((size_t)n * 4);
    float* invdeg = (float*)carve((size_t)n * 4);
    int*   bsums  = (int*)  carve(256 * 4);
    int*   boffs  = (int*)  carve(256 * 4);
    float* sums   = (float*)carve(64 * CH * 4);
    int*   cnts   = (int*)  carve(64 * 4);

    hipMemsetAsync(cnt,    0, (size_t)n * 4, stream);
    hipMemsetAsync(cursor, 0, (size_t)n * 4, stream);
    hipMemsetAsync(sums,   0, 64 * CH * 4, stream);
    hipMemsetAsync(cnts,   0, 64 * 4, stream);

    int nb = (n + 1023) / 1024;
    k_count      <<<(e + 255) / 256, 256, 0, stream>>>(dst, e, cnt);
    k_scan_reduce<<<nb, 256, 0, stream>>>(cnt, n, bsums);
    k_scan_bsums <<<1, 256, 0, stream>>>(bsums, nb, boffs);
    k_scan_final <<<nb, 256, 0, stream>>>(cnt, n, boffs, offs);
    k_norm       <<<(n + 255) / 256, 256, 0, stream>>>(cnt, n, dinv, invdeg, offs, e);
    k_fill       <<<(e + 255) / 256, 256, 0, stream>>>(src, dst, e, offs, cursor, col);

    dim3 ggemm((n + 63) / 64);
    dim3 gagg((n + 7) / 8);   // 8 half-waves per 256-thread block, half-wave per node

    // layer 1
    k_gemm<<<ggemm, 256, 0, stream>>>(x, W_in, h, n);
    k_agg <<<gagg, 256, 0, stream>>>(h, offs, col, dinv, invdeg, b_in, act, n);
    // layer 2
    k_gemm<<<ggemm, 256, 0, stream>>>(act, W_hid, h, n);
    k_agg <<<gagg, 256, 0, stream>>>(h, offs, col, dinv, invdeg, b_hid, act, n);
    // layer 3
    k_gemm<<<ggemm, 256, 0, stream>>>(act, W_hid + CH * CH, h, n);
    k_agg <<<gagg, 256, 0, stream>>>(h, offs, col, dinv, invdeg, b_hid + CH, act, n);

    // pool + head
    k_pool<<<(n + POOL_CHUNK - 1) / POOL_CHUNK, 128, 0, stream>>>(act, batch, n, sums, cnts);
    k_mlp <<<64, 128, 0, stream>>>(sums, cnts, Wm1, bm1, Wm2, bm2, (float*)d_out);
}

// Round 3
// 1159.695 us; speedup vs baseline: 1.3440x; 1.2953x over previous
//
#include <hip/hip_runtime.h>
#include <hip/hip_bf16.h>

// ---------------------------------------------------------------------------
// GCN forward: 3x { g = dinv.(act@W); act' = relu(dinv.(sum g[src] + g) + b) }
//              -> mean-pool(64) -> MLP(5)
// R2: bf16 storage for intermediates (f32 compute, f32 weights), dinv scale
// fused into GEMM epilogue so the agg hot loop is a PURE SUM of bf16 rows.
// R1 post-mortem: agg is fabric-BW-bound (3.77 TB/s on random row fetches,
// FETCH unchanged by ILP) -> halve the bytes.
// ---------------------------------------------------------------------------

#define CH 128

static __device__ __forceinline__ unsigned short f2bf(float f) {
    unsigned u = __float_as_uint(f);
    u += 0x7fffu + ((u >> 16) & 1u);          // round-to-nearest-even
    return (unsigned short)(u >> 16);
}
static __device__ __forceinline__ float bf_lo(unsigned u) { return __uint_as_float(u << 16); }
static __device__ __forceinline__ float bf_hi(unsigned u) { return __uint_as_float(u & 0xffff0000u); }

// ---------------- degree count ----------------
__global__ void k_count(const int* __restrict__ dst, int e, int* __restrict__ cnt) {
    int i = blockIdx.x * blockDim.x + threadIdx.x;
    if (i < e) atomicAdd(&cnt[dst[i]], 1);
}

// ---------------- hierarchical prefix scan (chunk=1024) ----------------
__global__ void k_scan_reduce(const int* __restrict__ cnt, int n, int* __restrict__ bsums) {
    __shared__ int sd[256];
    int b = blockIdx.x, t = threadIdx.x;
    int base = b * 1024;
    int s = 0;
    for (int i = t; i < 1024; i += 256) {
        int idx = base + i;
        if (idx < n) s += cnt[idx];
    }
    sd[t] = s; __syncthreads();
    for (int st = 128; st > 0; st >>= 1) {
        if (t < st) sd[t] += sd[t + st];
        __syncthreads();
    }
    if (t == 0) bsums[b] = sd[0];
}

__global__ void k_scan_bsums(const int* __restrict__ bsums, int nb, int* __restrict__ boffs) {
    __shared__ int sd[256];
    int t = threadIdx.x;
    int v = (t < nb) ? bsums[t] : 0;
    sd[t] = v; __syncthreads();
    for (int st = 1; st < 256; st <<= 1) {
        int x = (t >= st) ? sd[t - st] : 0;
        __syncthreads();
        sd[t] += x;
        __syncthreads();
    }
    if (t < nb) boffs[t] = sd[t] - v;   // exclusive
}

__global__ void k_scan_final(const int* __restrict__ cnt, int n,
                             const int* __restrict__ boffs, int* __restrict__ offs) {
    __shared__ int sd[256];
    int b = blockIdx.x, t = threadIdx.x;
    int base = b * 1024 + t * 4;
    int v[4]; int s = 0;
#pragma unroll
    for (int i = 0; i < 4; ++i) {
        int idx = base + i;
        v[i] = (idx < n) ? cnt[idx] : 0;
        s += v[i];
    }
    sd[t] = s; __syncthreads();
    for (int st = 1; st < 256; st <<= 1) {
        int x = (t >= st) ? sd[t - st] : 0;
        __syncthreads();
        sd[t] += x;
        __syncthreads();
    }
    int excl = sd[t] - s + boffs[b];
#pragma unroll
    for (int i = 0; i < 4; ++i) {
        int idx = base + i;
        if (idx < n) offs[idx] = excl;
        excl += v[i];
    }
}

// ---------------- norms + offs[n]=E ----------------
__global__ void k_norm(const int* __restrict__ cnt, int n,
                       float* __restrict__ dinv,
                       int* __restrict__ offs, int e) {
    int i = blockIdx.x * blockDim.x + threadIdx.x;
    if (i >= n) return;
    float d = (float)cnt[i] + 1.0f;
    dinv[i] = 1.0f / sqrtf(d);
    if (i == 0) offs[n] = e;
}

// ---------------- CSR fill ----------------
__global__ void k_fill(const int* __restrict__ src, const int* __restrict__ dst, int e,
                       const int* __restrict__ offs, int* __restrict__ cursor,
                       int* __restrict__ col) {
    int i = blockIdx.x * blockDim.x + threadIdx.x;
    if (i >= e) return;
    int d = dst[i];
    int pos = atomicAdd(&cursor[d], 1);
    col[offs[d] + pos] = src[i];
}

// ---------------- GEMM: G[N,128](bf16) = dinv . (A[N,128] @ W[128,128]) -----
// 512 threads, 128 rows/block, W f32 in LDS (64KB -> 2 blocks/CU, 4 w/SIMD).
// TA = float (layer 1 input x) or ushort (bf16 activations).
template <typename TA>
__global__ __launch_bounds__(512) void k_gemm(const TA* __restrict__ A,
                                              const float* __restrict__ W,
                                              const float* __restrict__ dinv,
                                              unsigned short* __restrict__ G, int n) {
    __shared__ float Ws[CH * CH];
    int t = threadIdx.x;
    for (int i = t * 4; i < CH * CH; i += 512 * 4)
        *(float4*)&Ws[i] = *(const float4*)&W[i];
    __syncthreads();

    int rowbase = blockIdx.x * 128;
    int cg = (t & 31) * 4;
    int rg = (t >> 5) * 8;
    float acc[8][4] = {{0.f}};

    for (int k4 = 0; k4 < 32; ++k4) {
        int k = k4 * 4;
        float4 w0 = *(float4*)&Ws[(k + 0) * CH + cg];
        float4 w1 = *(float4*)&Ws[(k + 1) * CH + cg];
        float4 w2 = *(float4*)&Ws[(k + 2) * CH + cg];
        float4 w3 = *(float4*)&Ws[(k + 3) * CH + cg];
#pragma unroll
        for (int j = 0; j < 8; ++j) {
            int row = rowbase + rg + j;
            int rr = row < n ? row : n - 1;           // clamp OOB reads
            float a0, a1, a2, a3;
            if constexpr (sizeof(TA) == 4) {
                float4 xv = *(const float4*)&((const float*)A)[(size_t)rr * CH + k];
                a0 = xv.x; a1 = xv.y; a2 = xv.z; a3 = xv.w;
            } else {
                uint2 uv = *(const uint2*)&((const unsigned short*)A)[(size_t)rr * CH + k];
                a0 = bf_lo(uv.x); a1 = bf_hi(uv.x);
                a2 = bf_lo(uv.y); a3 = bf_hi(uv.y);
            }
            acc[j][0] += a0 * w0.x + a1 * w1.x + a2 * w2.x + a3 * w3.x;
            acc[j][1] += a0 * w0.y + a1 * w1.y + a2 * w2.y + a3 * w3.y;
            acc[j][2] += a0 * w0.z + a1 * w1.z + a2 * w2.z + a3 * w3.z;
            acc[j][3] += a0 * w0.w + a1 * w1.w + a2 * w2.w + a3 * w3.w;
        }
    }
#pragma unroll
    for (int j = 0; j < 8; ++j) {
        int row = rowbase + rg + j;
        if (row < n) {
            float s = dinv[row];
            ushort4 o;
            o.x = f2bf(acc[j][0] * s);
            o.y = f2bf(acc[j][1] * s);
            o.z = f2bf(acc[j][2] * s);
            o.w = f2bf(acc[j][3] * s);
            *(ushort4*)&G[(size_t)row * CH + cg] = o;
        }
    }
}

// ---------------- aggregation: wave per node, lane = 2 bf16 channels --------
// act[i] = relu( dinv[i] * (sum_{src in N(i)} g[src] + g[i]) + b )   (bf16)
__global__ __launch_bounds__(256) void k_agg(const unsigned short* __restrict__ g,
                                             const int* __restrict__ offs,
                                             const int* __restrict__ col,
                                             const float* __restrict__ dinv,
                                             const float* __restrict__ bias,
                                             unsigned short* __restrict__ act, int n) {
    int node = (int)((blockIdx.x * (unsigned)blockDim.x + threadIdx.x) >> 6);
    int lane = threadIdx.x & 63;
    if (node >= n) return;
    int beg = offs[node], end = offs[node + 1];

    const unsigned* gp = (const unsigned*)g;   // one dword = 2 bf16 channels
    float ax = 0.f, ay = 0.f;

    for (int e0 = beg; e0 < end; e0 += 64) {
        int cnt = end - e0; if (cnt > 64) cnt = 64;
        int s_l = (lane < cnt) ? col[e0 + lane] : 0;
        int j = 0;
        for (; j + 4 <= cnt; j += 4) {
            int s0 = __shfl(s_l, j + 0);
            int s1 = __shfl(s_l, j + 1);
            int s2 = __shfl(s_l, j + 2);
            int s3 = __shfl(s_l, j + 3);
            unsigned u0 = gp[(size_t)s0 * 64 + lane];
            unsigned u1 = gp[(size_t)s1 * 64 + lane];
            unsigned u2 = gp[(size_t)s2 * 64 + lane];
            unsigned u3 = gp[(size_t)s3 * 64 + lane];
            ax += bf_lo(u0); ay += bf_hi(u0);
            ax += bf_lo(u1); ay += bf_hi(u1);
            ax += bf_lo(u2); ay += bf_hi(u2);
            ax += bf_lo(u3); ay += bf_hi(u3);
        }
        for (; j < cnt; ++j) {
            int s = __shfl(s_l, j);
            unsigned u = gp[(size_t)s * 64 + lane];
            ax += bf_lo(u); ay += bf_hi(u);
        }
    }

    unsigned us = gp[(size_t)node * 64 + lane];   // self-loop term
    ax += bf_lo(us); ay += bf_hi(us);

    float di = dinv[node];
    float2 b2 = ((const float2*)bias)[lane];
    float ox = fmaxf(ax * di + b2.x, 0.f);
    float oy = fmaxf(ay * di + b2.y, 0.f);
    unsigned o = (unsigned)f2bf(ox) | ((unsigned)f2bf(oy) << 16);
    ((unsigned*)act)[(size_t)node * 64 + lane] = o;
}

// ---------------- pooling: sorted batch ids, per-block running sums ---------
#define POOL_CHUNK 512
__global__ __launch_bounds__(128) void k_pool(const unsigned short* __restrict__ act,
                                              const int* __restrict__ batch, int n,
                                              float* __restrict__ sums, int* __restrict__ cnts) {
    int b = blockIdx.x, c = threadIdx.x;
    int beg = b * POOL_CHUNK;
    int end = beg + POOL_CHUNK; if (end > n) end = n;
    if (beg >= end) return;

    float acc = 0.f;
    int g = batch[beg];
    int cstart = beg;
    for (int i = beg; i < end; ++i) {
        int gi = batch[i];
        if (gi != g) {
            atomicAdd(&sums[g * CH + c], acc);
            if (c == 0) atomicAdd(&cnts[g], i - cstart);
            acc = 0.f; g = gi; cstart = i;
        }
        acc += __uint_as_float((unsigned)act[(size_t)i * CH + c] << 16);
    }
    atomicAdd(&sums[g * CH + c], acc);
    if (c == 0) atomicAdd(&cnts[g], end - cstart);
}

// ---------------- MLP head ----------------
__global__ __launch_bounds__(128) void k_mlp(const float* __restrict__ sums,
                                             const int* __restrict__ cnts,
                                             const float* __restrict__ Wm1,
                                             const float* __restrict__ bm1,
                                             const float* __restrict__ Wm2,
                                             const float* __restrict__ bm2,
                                             float* __restrict__ out) {
    int g = blockIdx.x, c = threadIdx.x;
    __shared__ float p[CH];
    __shared__ float hid[CH];
    float invc = 1.0f / fmaxf((float)cnts[g], 1.0f);
    p[c] = sums[g * CH + c] * invc;
    __syncthreads();
    float acc = bm1[c];
    for (int k = 0; k < CH; ++k) acc += p[k] * Wm1[k * CH + c];
    hid[c] = fmaxf(acc, 0.f);
    __syncthreads();
    if (c < 5) {
        float o = bm2[c];
        for (int k = 0; k < CH; ++k) o += hid[k] * Wm2[k * 5 + c];
        out[g * 5 + c] = o;
    }
}

// ---------------------------------------------------------------------------
extern "C" void kernel_launch(void* const* d_in, const int* in_sizes, int n_in,
                              void* d_out, int out_size, void* d_ws, size_t ws_size,
                              hipStream_t stream) {
    const float* x     = (const float*)d_in[0];
    const int*   ei    = (const int*)d_in[1];
    const int*   batch = (const int*)d_in[2];
    const float* W_in  = (const float*)d_in[3];
    const float* b_in  = (const float*)d_in[4];
    const float* W_hid = (const float*)d_in[5];
    const float* b_hid = (const float*)d_in[6];
    const float* Wm1   = (const float*)d_in[7];
    const float* bm1   = (const float*)d_in[8];
    const float* Wm2   = (const float*)d_in[9];
    const float* bm2   = (const float*)d_in[10];

    int n = in_sizes[0] / CH;       // 100000
    int e = in_sizes[1] / 2;        // 3200000
    const int* src = ei;
    const int* dst = ei + e;

    // workspace carve (256B aligned)
    char* p = (char*)d_ws;
    auto carve = [&](size_t bytes) {
        void* r = (void*)p;
        p += (bytes + 255) & ~(size_t)255;
        return r;
    };
    unsigned short* g   = (unsigned short*)carve((size_t)n * CH * 2);
    unsigned short* act = (unsigned short*)carve((size_t)n * CH * 2);
    int*   col    = (int*)  carve((size_t)e * 4);
    int*   cnt    = (int*)  carve((size_t)n * 4);
    int*   cursor = (int*)  carve((size_t)n * 4);
    int*   offs   = (int*)  carve((size_t)(n + 1) * 4);
    float* dinv   = (float*)carve((size_t)n * 4);
    int*   bsums  = (int*)  carve(256 * 4);
    int*   boffs  = (int*)  carve(256 * 4);
    float* sums   = (float*)carve(64 * CH * 4);
    int*   cnts   = (int*)  carve(64 * 4);

    hipMemsetAsync(cnt,    0, (size_t)n * 4, stream);
    hipMemsetAsync(cursor, 0, (size_t)n * 4, stream);
    hipMemsetAsync(sums,   0, 64 * CH * 4, stream);
    hipMemsetAsync(cnts,   0, 64 * 4, stream);

    int nb = (n + 1023) / 1024;
    k_count      <<<(e + 255) / 256, 256, 0, stream>>>(dst, e, cnt);
    k_scan_reduce<<<nb, 256, 0, stream>>>(cnt, n, bsums);
    k_scan_bsums <<<1, 256, 0, stream>>>(bsums, nb, boffs);
    k_scan_final <<<nb, 256, 0, stream>>>(cnt, n, boffs, offs);
    k_norm       <<<(n + 255) / 256, 256, 0, stream>>>(cnt, n, dinv, offs, e);
    k_fill       <<<(e + 255) / 256, 256, 0, stream>>>(src, dst, e, offs, cursor, col);

    dim3 ggemm((n + 127) / 128);
    dim3 gagg((n + 3) / 4);   // 4 waves per 256-thread block, wave per node

    // layer 1 (f32 input x)
    k_gemm<float>         <<<ggemm, 512, 0, stream>>>(x, W_in, dinv, g, n);
    k_agg                 <<<gagg, 256, 0, stream>>>(g, offs, col, dinv, b_in, act, n);
    // layer 2
    k_gemm<unsigned short><<<ggemm, 512, 0, stream>>>(act, W_hid, dinv, g, n);
    k_agg                 <<<gagg, 256, 0, stream>>>(g, offs, col, dinv, b_hid, act, n);
    // layer 3
    k_gemm<unsigned short><<<ggemm, 512, 0, stream>>>(act, W_hid + CH * CH, dinv, g, n);
    k_agg                 <<<gagg, 256, 0, stream>>>(g, offs, col, dinv, b_hid + CH, act, n);

    // pool + head
    k_pool<<<(n + POOL_CHUNK - 1) / POOL_CHUNK, 128, 0, stream>>>(act, batch, n, sums, cnts);
    k_mlp <<<64, 128, 0, stream>>>(sums, cnts, Wm1, bm1, Wm2, bm2, (float*)d_out);
}

// Round 4
// 1112.290 us; speedup vs baseline: 1.4012x; 1.0426x over previous
//
#include <hip/hip_runtime.h>
#include <hip/hip_bf16.h>

// ---------------------------------------------------------------------------
// GCN forward: 3x { g = dinv.(act@W); act' = relu(dinv.(sum g[src] + g) + b) }
//              -> mean-pool(64) -> MLP(5)
// R3: k_count/k_fill partitioned by dst-range into 8 XCD-affine chunks
// (group = blockIdx&7). R2 post-mortem: k_fill WRITE_SIZE=197MB for 12.8MB of
// payload (15x writeback amplification, per-XCD L2 thrash on scattered 4B
// writes). Confining each group's write region to 1.6MB makes it L2-resident
// on one XCD -> ~1x writeback. Reads are L3-resident streams.
// ---------------------------------------------------------------------------

#define CH 128
#define NCHUNK 8
#define BLKS_PER_CHUNK 64

static __device__ __forceinline__ unsigned short f2bf(float f) {
    unsigned u = __float_as_uint(f);
    u += 0x7fffu + ((u >> 16) & 1u);          // round-to-nearest-even
    return (unsigned short)(u >> 16);
}
static __device__ __forceinline__ float bf_lo(unsigned u) { return __uint_as_float(u << 16); }
static __device__ __forceinline__ float bf_hi(unsigned u) { return __uint_as_float(u & 0xffff0000u); }

// ---------------- degree count (dst-range partitioned, XCD-affine) ----------
__global__ __launch_bounds__(256) void k_count(const int* __restrict__ dst, int e,
                                               int* __restrict__ cnt, int n) {
    int grp = blockIdx.x & (NCHUNK - 1);
    int b2  = blockIdx.x >> 3;
    int chunk = (n + NCHUNK - 1) / NCHUNK;
    int lo = grp * chunk;
    int hi = lo + chunk; if (hi > n) hi = n;
    int stride = BLKS_PER_CHUNK * 256;
    for (int i = b2 * 256 + threadIdx.x; i < e; i += stride) {
        int d = dst[i];
        if (d >= lo && d < hi) atomicAdd(&cnt[d], 1);
    }
}

// ---------------- hierarchical prefix scan (chunk=1024) ----------------
__global__ void k_scan_reduce(const int* __restrict__ cnt, int n, int* __restrict__ bsums) {
    __shared__ int sd[256];
    int b = blockIdx.x, t = threadIdx.x;
    int base = b * 1024;
    int s = 0;
    for (int i = t; i < 1024; i += 256) {
        int idx = base + i;
        if (idx < n) s += cnt[idx];
    }
    sd[t] = s; __syncthreads();
    for (int st = 128; st > 0; st >>= 1) {
        if (t < st) sd[t] += sd[t + st];
        __syncthreads();
    }
    if (t == 0) bsums[b] = sd[0];
}

__global__ void k_scan_bsums(const int* __restrict__ bsums, int nb, int* __restrict__ boffs) {
    __shared__ int sd[256];
    int t = threadIdx.x;
    int v = (t < nb) ? bsums[t] : 0;
    sd[t] = v; __syncthreads();
    for (int st = 1; st < 256; st <<= 1) {
        int x = (t >= st) ? sd[t - st] : 0;
        __syncthreads();
        sd[t] += x;
        __syncthreads();
    }
    if (t < nb) boffs[t] = sd[t] - v;   // exclusive
}

__global__ void k_scan_final(const int* __restrict__ cnt, int n,
                             const int* __restrict__ boffs, int* __restrict__ offs) {
    __shared__ int sd[256];
    int b = blockIdx.x, t = threadIdx.x;
    int base = b * 1024 + t * 4;
    int v[4]; int s = 0;
#pragma unroll
    for (int i = 0; i < 4; ++i) {
        int idx = base + i;
        v[i] = (idx < n) ? cnt[idx] : 0;
        s += v[i];
    }
    sd[t] = s; __syncthreads();
    for (int st = 1; st < 256; st <<= 1) {
        int x = (t >= st) ? sd[t - st] : 0;
        __syncthreads();
        sd[t] += x;
        __syncthreads();
    }
    int excl = sd[t] - s + boffs[b];
#pragma unroll
    for (int i = 0; i < 4; ++i) {
        int idx = base + i;
        if (idx < n) offs[idx] = excl;
        excl += v[i];
    }
}

// ---------------- norms + offs[n]=E ----------------
__global__ void k_norm(const int* __restrict__ cnt, int n,
                       float* __restrict__ dinv,
                       int* __restrict__ offs, int e) {
    int i = blockIdx.x * blockDim.x + threadIdx.x;
    if (i >= n) return;
    float d = (float)cnt[i] + 1.0f;
    dinv[i] = 1.0f / sqrtf(d);
    if (i == 0) offs[n] = e;
}

// ---------------- CSR fill (dst-range partitioned, XCD-affine) --------------
__global__ __launch_bounds__(256) void k_fill(const int* __restrict__ src,
                                              const int* __restrict__ dst, int e,
                                              const int* __restrict__ offs,
                                              int* __restrict__ cursor,
                                              int* __restrict__ col, int n) {
    int grp = blockIdx.x & (NCHUNK - 1);
    int b2  = blockIdx.x >> 3;
    int chunk = (n + NCHUNK - 1) / NCHUNK;
    int lo = grp * chunk;
    int hi = lo + chunk; if (hi > n) hi = n;
    int stride = BLKS_PER_CHUNK * 256;
    for (int i = b2 * 256 + threadIdx.x; i < e; i += stride) {
        int d = dst[i];
        if (d >= lo && d < hi) {
            int s = src[i];
            int pos = atomicAdd(&cursor[d], 1);
            col[offs[d] + pos] = s;
        }
    }
}

// ---------------- GEMM: G[N,128](bf16) = dinv . (A[N,128] @ W[128,128]) -----
// 512 threads, 128 rows/block, W f32 in LDS (64KB -> 2 blocks/CU, 4 w/SIMD).
template <typename TA>
__global__ __launch_bounds__(512) void k_gemm(const TA* __restrict__ A,
                                              const float* __restrict__ W,
                                              const float* __restrict__ dinv,
                                              unsigned short* __restrict__ G, int n) {
    __shared__ float Ws[CH * CH];
    int t = threadIdx.x;
    for (int i = t * 4; i < CH * CH; i += 512 * 4)
        *(float4*)&Ws[i] = *(const float4*)&W[i];
    __syncthreads();

    int rowbase = blockIdx.x * 128;
    int cg = (t & 31) * 4;
    int rg = (t >> 5) * 8;
    float acc[8][4] = {{0.f}};

    for (int k4 = 0; k4 < 32; ++k4) {
        int k = k4 * 4;
        float4 w0 = *(float4*)&Ws[(k + 0) * CH + cg];
        float4 w1 = *(float4*)&Ws[(k + 1) * CH + cg];
        float4 w2 = *(float4*)&Ws[(k + 2) * CH + cg];
        float4 w3 = *(float4*)&Ws[(k + 3) * CH + cg];
#pragma unroll
        for (int j = 0; j < 8; ++j) {
            int row = rowbase + rg + j;
            int rr = row < n ? row : n - 1;           // clamp OOB reads
            float a0, a1, a2, a3;
            if constexpr (sizeof(TA) == 4) {
                float4 xv = *(const float4*)&((const float*)A)[(size_t)rr * CH + k];
                a0 = xv.x; a1 = xv.y; a2 = xv.z; a3 = xv.w;
            } else {
                uint2 uv = *(const uint2*)&((const unsigned short*)A)[(size_t)rr * CH + k];
                a0 = bf_lo(uv.x); a1 = bf_hi(uv.x);
                a2 = bf_lo(uv.y); a3 = bf_hi(uv.y);
            }
            acc[j][0] += a0 * w0.x + a1 * w1.x + a2 * w2.x + a3 * w3.x;
            acc[j][1] += a0 * w0.y + a1 * w1.y + a2 * w2.y + a3 * w3.y;
            acc[j][2] += a0 * w0.z + a1 * w1.z + a2 * w2.z + a3 * w3.z;
            acc[j][3] += a0 * w0.w + a1 * w1.w + a2 * w2.w + a3 * w3.w;
        }
    }
#pragma unroll
    for (int j = 0; j < 8; ++j) {
        int row = rowbase + rg + j;
        if (row < n) {
            float s = dinv[row];
            ushort4 o;
            o.x = f2bf(acc[j][0] * s);
            o.y = f2bf(acc[j][1] * s);
            o.z = f2bf(acc[j][2] * s);
            o.w = f2bf(acc[j][3] * s);
            *(ushort4*)&G[(size_t)row * CH + cg] = o;
        }
    }
}

// ---------------- aggregation: wave per node, lane = 2 bf16 channels --------
// act[i] = relu( dinv[i] * (sum_{src in N(i)} g[src] + g[i]) + b )   (bf16)
__global__ __launch_bounds__(256) void k_agg(const unsigned short* __restrict__ g,
                                             const int* __restrict__ offs,
                                             const int* __restrict__ col,
                                             const float* __restrict__ dinv,
                                             const float* __restrict__ bias,
                                             unsigned short* __restrict__ act, int n) {
    int node = (int)((blockIdx.x * (unsigned)blockDim.x + threadIdx.x) >> 6);
    int lane = threadIdx.x & 63;
    if (node >= n) return;
    int beg = offs[node], end = offs[node + 1];

    const unsigned* gp = (const unsigned*)g;   // one dword = 2 bf16 channels
    float ax = 0.f, ay = 0.f;

    for (int e0 = beg; e0 < end; e0 += 64) {
        int cnt = end - e0; if (cnt > 64) cnt = 64;
        int s_l = (lane < cnt) ? col[e0 + lane] : 0;
        int j = 0;
        for (; j + 4 <= cnt; j += 4) {
            int s0 = __shfl(s_l, j + 0);
            int s1 = __shfl(s_l, j + 1);
            int s2 = __shfl(s_l, j + 2);
            int s3 = __shfl(s_l, j + 3);
            unsigned u0 = gp[(size_t)s0 * 64 + lane];
            unsigned u1 = gp[(size_t)s1 * 64 + lane];
            unsigned u2 = gp[(size_t)s2 * 64 + lane];
            unsigned u3 = gp[(size_t)s3 * 64 + lane];
            ax += bf_lo(u0); ay += bf_hi(u0);
            ax += bf_lo(u1); ay += bf_hi(u1);
            ax += bf_lo(u2); ay += bf_hi(u2);
            ax += bf_lo(u3); ay += bf_hi(u3);
        }
        for (; j < cnt; ++j) {
            int s = __shfl(s_l, j);
            unsigned u = gp[(size_t)s * 64 + lane];
            ax += bf_lo(u); ay += bf_hi(u);
        }
    }

    unsigned us = gp[(size_t)node * 64 + lane];   // self-loop term
    ax += bf_lo(us); ay += bf_hi(us);

    float di = dinv[node];
    float2 b2 = ((const float2*)bias)[lane];
    float ox = fmaxf(ax * di + b2.x, 0.f);
    float oy = fmaxf(ay * di + b2.y, 0.f);
    unsigned o = (unsigned)f2bf(ox) | ((unsigned)f2bf(oy) << 16);
    ((unsigned*)act)[(size_t)node * 64 + lane] = o;
}

// ---------------- pooling: sorted batch ids, per-block running sums ---------
#define POOL_CHUNK 512
__global__ __launch_bounds__(128) void k_pool(const unsigned short* __restrict__ act,
                                              const int* __restrict__ batch, int n,
                                              float* __restrict__ sums, int* __restrict__ cnts) {
    int b = blockIdx.x, c = threadIdx.x;
    int beg = b * POOL_CHUNK;
    int end = beg + POOL_CHUNK; if (end > n) end = n;
    if (beg >= end) return;

    float acc = 0.f;
    int g = batch[beg];
    int cstart = beg;
    for (int i = beg; i < end; ++i) {
        int gi = batch[i];
        if (gi != g) {
            atomicAdd(&sums[g * CH + c], acc);
            if (c == 0) atomicAdd(&cnts[g], i - cstart);
            acc = 0.f; g = gi; cstart = i;
        }
        acc += __uint_as_float((unsigned)act[(size_t)i * CH + c] << 16);
    }
    atomicAdd(&sums[g * CH + c], acc);
    if (c == 0) atomicAdd(&cnts[g], end - cstart);
}

// ---------------- MLP head ----------------
__global__ __launch_bounds__(128) void k_mlp(const float* __restrict__ sums,
                                             const int* __restrict__ cnts,
                                             const float* __restrict__ Wm1,
                                             const float* __restrict__ bm1,
                                             const float* __restrict__ Wm2,
                                             const float* __restrict__ bm2,
                                             float* __restrict__ out) {
    int g = blockIdx.x, c = threadIdx.x;
    __shared__ float p[CH];
    __shared__ float hid[CH];
    float invc = 1.0f / fmaxf((float)cnts[g], 1.0f);
    p[c] = sums[g * CH + c] * invc;
    __syncthreads();
    float acc = bm1[c];
    for (int k = 0; k < CH; ++k) acc += p[k] * Wm1[k * CH + c];
    hid[c] = fmaxf(acc, 0.f);
    __syncthreads();
    if (c < 5) {
        float o = bm2[c];
        for (int k = 0; k < CH; ++k) o += hid[k] * Wm2[k * 5 + c];
        out[g * 5 + c] = o;
    }
}

// ---------------------------------------------------------------------------
extern "C" void kernel_launch(void* const* d_in, const int* in_sizes, int n_in,
                              void* d_out, int out_size, void* d_ws, size_t ws_size,
                              hipStream_t stream) {
    const float* x     = (const float*)d_in[0];
    const int*   ei    = (const int*)d_in[1];
    const int*   batch = (const int*)d_in[2];
    const float* W_in  = (const float*)d_in[3];
    const float* b_in  = (const float*)d_in[4];
    const float* W_hid = (const float*)d_in[5];
    const float* b_hid = (const float*)d_in[6];
    const float* Wm1   = (const float*)d_in[7];
    const float* bm1   = (const float*)d_in[8];
    const float* Wm2   = (const float*)d_in[9];
    const float* bm2   = (const float*)d_in[10];

    int n = in_sizes[0] / CH;       // 100000
    int e = in_sizes[1] / 2;        // 3200000
    const int* src = ei;
    const int* dst = ei + e;

    // workspace carve (256B aligned)
    char* p = (char*)d_ws;
    auto carve = [&](size_t bytes) {
        void* r = (void*)p;
        p += (bytes + 255) & ~(size_t)255;
        return r;
    };
    unsigned short* g   = (unsigned short*)carve((size_t)n * CH * 2);
    unsigned short* act = (unsigned short*)carve((size_t)n * CH * 2);
    int*   col    = (int*)  carve((size_t)e * 4);
    int*   cnt    = (int*)  carve((size_t)n * 4);
    int*   cursor = (int*)  carve((size_t)n * 4);
    int*   offs   = (int*)  carve((size_t)(n + 1) * 4);
    float* dinv   = (float*)carve((size_t)n * 4);
    int*   bsums  = (int*)  carve(256 * 4);
    int*   boffs  = (int*)  carve(256 * 4);
    float* sums   = (float*)carve(64 * CH * 4);
    int*   cnts   = (int*)  carve(64 * 4);

    hipMemsetAsync(cnt,    0, (size_t)n * 4, stream);
    hipMemsetAsync(cursor, 0, (size_t)n * 4, stream);
    hipMemsetAsync(sums,   0, 64 * CH * 4, stream);
    hipMemsetAsync(cnts,   0, 64 * 4, stream);

    int nb = (n + 1023) / 1024;
    k_count      <<<NCHUNK * BLKS_PER_CHUNK, 256, 0, stream>>>(dst, e, cnt, n);
    k_scan_reduce<<<nb, 256, 0, stream>>>(cnt, n, bsums);
    k_scan_bsums <<<1, 256, 0, stream>>>(bsums, nb, boffs);
    k_scan_final <<<nb, 256, 0, stream>>>(cnt, n, boffs, offs);
    k_norm       <<<(n + 255) / 256, 256, 0, stream>>>(cnt, n, dinv, offs, e);
    k_fill       <<<NCHUNK * BLKS_PER_CHUNK, 256, 0, stream>>>(src, dst, e, offs, cursor, col, n);

    dim3 ggemm((n + 127) / 128);
    dim3 gagg((n + 3) / 4);   // 4 waves per 256-thread block, wave per node

    // layer 1 (f32 input x)
    k_gemm<float>         <<<ggemm, 512, 0, stream>>>(x, W_in, dinv, g, n);
    k_agg                 <<<gagg, 256, 0, stream>>>(g, offs, col, dinv, b_in, act, n);
    // layer 2
    k_gemm<unsigned short><<<ggemm, 512, 0, stream>>>(act, W_hid, dinv, g, n);
    k_agg                 <<<gagg, 256, 0, stream>>>(g, offs, col, dinv, b_hid, act, n);
    // layer 3
    k_gemm<unsigned short><<<ggemm, 512, 0, stream>>>(act, W_hid + CH * CH, dinv, g, n);
    k_agg                 <<<gagg, 256, 0, stream>>>(g, offs, col, dinv, b_hid + CH, act, n);

    // pool + head
    k_pool<<<(n + POOL_CHUNK - 1) / POOL_CHUNK, 128, 0, stream>>>(act, batch, n, sums, cnts);
    k_mlp <<<64, 128, 0, stream>>>(sums, cnts, Wm1, bm1, Wm2, bm2, (float*)d_out);
}